// Round 1
// baseline (973.377 us; speedup 1.0000x reference)
//
#include <hip/hip_runtime.h>

#define DIM 384
#define NSEG 1024

// ---------------- counting sort ----------------

__global__ void hist_kernel(const int* __restrict__ ix, int* __restrict__ hist, int H) {
    int i = blockIdx.x * blockDim.x + threadIdx.x;
    if (i < H) atomicAdd(&hist[ix[i]], 1);
}

__global__ void scan_kernel(const int* __restrict__ hist, int* __restrict__ seg_start,
                            int* __restrict__ cursor) {
    __shared__ int tmp[NSEG];
    int t = threadIdx.x;
    int v = hist[t];
    tmp[t] = v;
    __syncthreads();
    for (int off = 1; off < NSEG; off <<= 1) {
        int add = (t >= off) ? tmp[t - off] : 0;
        __syncthreads();
        tmp[t] += add;
        __syncthreads();
    }
    int incl = tmp[t];
    seg_start[t] = incl - v;
    cursor[t]    = incl - v;
    if (t == NSEG - 1) seg_start[NSEG] = incl;
}

__global__ void scatter_kernel(const int* __restrict__ ix, int* __restrict__ cursor,
                               int* __restrict__ order, int H) {
    int i = blockIdx.x * blockDim.x + threadIdx.x;
    if (i < H) {
        int p = atomicAdd(&cursor[ix[i]], 1);
        order[p] = i;
    }
}

// ---------------- fused f/g GEMM + segment reduce ----------------
// grid: (NSEG, 3). Block handles one segment x one 128-channel tile.
// Computes fx = x@f_w^T+f_b, gx = x@g_w^T+g_b for the segment's rows,
// w = exp(clip(gx)), reduces sum(w) and sum((fx+fb)*w) over rows in-block,
// writes num[seg][c] = sum_fw / max(sum_w, 1e-9). No global atomics.
__global__ __launch_bounds__(256) void seg_gemm_kernel(
    const float* __restrict__ x,
    const float* __restrict__ f_w, const float* __restrict__ f_b,
    const float* __restrict__ g_w, const float* __restrict__ g_b,
    const int* __restrict__ order, const int* __restrict__ seg_start,
    float* __restrict__ num) {
    const int seg = blockIdx.x;
    const int c0  = blockIdx.y * 128;
    const int tid = threadIdx.x;
    const int ty  = tid >> 4;   // 0..15 (row group)
    const int tx  = tid & 15;   // 0..15 (col group)

    __shared__ float As[16][64];
    __shared__ float Bf[16][128];
    __shared__ float Bg[16][128];
    __shared__ float red[16][128];
    __shared__ float run_w[128];
    __shared__ float run_fw[128];

    const int p0  = seg_start[seg];
    const int p1  = seg_start[seg + 1];
    const int cnt = p1 - p0;

    if (tid < 128) { run_w[tid] = 0.f; run_fw[tid] = 0.f; }

    float fb[8], gb[8];
#pragma unroll
    for (int j = 0; j < 8; j++) {
        fb[j] = f_b[c0 + tx * 8 + j];
        gb[j] = g_b[c0 + tx * 8 + j];
    }

    for (int chunk = 0; chunk < cnt; chunk += 64) {
        float accf[4][8], accg[4][8];
#pragma unroll
        for (int i = 0; i < 4; i++)
#pragma unroll
            for (int j = 0; j < 8; j++) { accf[i][j] = 0.f; accg[i][j] = 0.f; }

        for (int k0 = 0; k0 < DIM; k0 += 16) {
            __syncthreads();
            // A tile: 64 rows x 16 k (transposed into LDS)
            {
                int m  = tid >> 2;
                int kq = (tid & 3) << 2;
                int p  = p0 + chunk + m;
                if (p > p1 - 1) p = p1 - 1;   // clamp; masked in epilogue
                int r = order[p];
                float4 v = *(const float4*)(x + (size_t)r * DIM + k0 + kq);
                As[kq + 0][m] = v.x; As[kq + 1][m] = v.y;
                As[kq + 2][m] = v.z; As[kq + 3][m] = v.w;
            }
            // B tiles: 128 channels x 16 k for f_w and g_w
            {
                int c  = tid >> 1;
                int kq = (tid & 1) << 3;
                const float* fp = f_w + (size_t)(c0 + c) * DIM + k0 + kq;
                float4 v0 = *(const float4*)fp;
                float4 v1 = *(const float4*)(fp + 4);
                Bf[kq + 0][c] = v0.x; Bf[kq + 1][c] = v0.y;
                Bf[kq + 2][c] = v0.z; Bf[kq + 3][c] = v0.w;
                Bf[kq + 4][c] = v1.x; Bf[kq + 5][c] = v1.y;
                Bf[kq + 6][c] = v1.z; Bf[kq + 7][c] = v1.w;
                const float* gp = g_w + (size_t)(c0 + c) * DIM + k0 + kq;
                v0 = *(const float4*)gp;
                v1 = *(const float4*)(gp + 4);
                Bg[kq + 0][c] = v0.x; Bg[kq + 1][c] = v0.y;
                Bg[kq + 2][c] = v0.z; Bg[kq + 3][c] = v0.w;
                Bg[kq + 4][c] = v1.x; Bg[kq + 5][c] = v1.y;
                Bg[kq + 6][c] = v1.z; Bg[kq + 7][c] = v1.w;
            }
            __syncthreads();
#pragma unroll
            for (int kk = 0; kk < 16; kk++) {
                float a[4], bf[8], bg[8];
#pragma unroll
                for (int i = 0; i < 4; i++) a[i] = As[kk][ty * 4 + i];
#pragma unroll
                for (int j = 0; j < 8; j++) { bf[j] = Bf[kk][tx * 8 + j]; bg[j] = Bg[kk][tx * 8 + j]; }
#pragma unroll
                for (int i = 0; i < 4; i++)
#pragma unroll
                    for (int j = 0; j < 8; j++) {
                        accf[i][j] += a[i] * bf[j];
                        accg[i][j] += a[i] * bg[j];
                    }
            }
        }

        // epilogue: w = exp(clip(gx)), per-thread partial sums over its 4 rows
        float sw[8], sfw[8];
#pragma unroll
        for (int j = 0; j < 8; j++) { sw[j] = 0.f; sfw[j] = 0.f; }
#pragma unroll
        for (int i = 0; i < 4; i++) {
            int m = ty * 4 + i;
            if (chunk + m < cnt) {
#pragma unroll
                for (int j = 0; j < 8; j++) {
                    float gx = accg[i][j] + gb[j];
                    gx = fmaxf(-50.f, fminf(50.f, gx));
                    float w = __expf(gx);
                    sw[j]  += w;
                    sfw[j] += (accf[i][j] + fb[j]) * w;
                }
            }
        }
        // cross-thread reduce over ty (16 row-groups), two rounds
        __syncthreads();
#pragma unroll
        for (int j = 0; j < 8; j++) red[ty][tx * 8 + j] = sw[j];
        __syncthreads();
        for (int s = 8; s > 0; s >>= 1) {
            if (ty < s) {
#pragma unroll
                for (int j = 0; j < 8; j++) red[ty][tx * 8 + j] += red[ty + s][tx * 8 + j];
            }
            __syncthreads();
        }
        if (ty == 0) {
#pragma unroll
            for (int j = 0; j < 8; j++) run_w[tx * 8 + j] += red[0][tx * 8 + j];
        }
        __syncthreads();
#pragma unroll
        for (int j = 0; j < 8; j++) red[ty][tx * 8 + j] = sfw[j];
        __syncthreads();
        for (int s = 8; s > 0; s >>= 1) {
            if (ty < s) {
#pragma unroll
                for (int j = 0; j < 8; j++) red[ty][tx * 8 + j] += red[ty + s][tx * 8 + j];
            }
            __syncthreads();
        }
        if (ty == 0) {
#pragma unroll
            for (int j = 0; j < 8; j++) run_fw[tx * 8 + j] += red[0][tx * 8 + j];
        }
        __syncthreads();
    }

    __syncthreads();
    if (tid < 128) {
        float d = run_w[tid];
        d = d > 1e-9f ? d : 1e-9f;
        num[(size_t)seg * DIM + c0 + tid] = run_fw[tid] / d;
    }
}

// ---------------- small h GEMM: z = num @ h_w^T + h_b ----------------
__global__ __launch_bounds__(256) void hgemm_kernel(
    const float* __restrict__ num, const float* __restrict__ h_w,
    const float* __restrict__ h_b, float* __restrict__ z) {
    const int m0 = blockIdx.x * 64;
    const int c0 = blockIdx.y * 64;
    const int tid = threadIdx.x;
    const int ty = tid >> 4, tx = tid & 15;
    __shared__ float As[16][64];
    __shared__ float Bs[16][64];
    float acc[4][4];
#pragma unroll
    for (int i = 0; i < 4; i++)
#pragma unroll
        for (int j = 0; j < 4; j++) acc[i][j] = 0.f;

    for (int k0 = 0; k0 < DIM; k0 += 16) {
        __syncthreads();
        {
            int m  = tid >> 2;
            int kq = (tid & 3) << 2;
            float4 v = *(const float4*)(num + (size_t)(m0 + m) * DIM + k0 + kq);
            As[kq + 0][m] = v.x; As[kq + 1][m] = v.y;
            As[kq + 2][m] = v.z; As[kq + 3][m] = v.w;
            float4 w = *(const float4*)(h_w + (size_t)(c0 + m) * DIM + k0 + kq);
            Bs[kq + 0][m] = w.x; Bs[kq + 1][m] = w.y;
            Bs[kq + 2][m] = w.z; Bs[kq + 3][m] = w.w;
        }
        __syncthreads();
#pragma unroll
        for (int kk = 0; kk < 16; kk++) {
            float a[4], b[4];
#pragma unroll
            for (int i = 0; i < 4; i++) a[i] = As[kk][ty * 4 + i];
#pragma unroll
            for (int j = 0; j < 4; j++) b[j] = Bs[kk][tx * 4 + j];
#pragma unroll
            for (int i = 0; i < 4; i++)
#pragma unroll
                for (int j = 0; j < 4; j++) acc[i][j] += a[i] * b[j];
        }
    }
#pragma unroll
    for (int i = 0; i < 4; i++)
#pragma unroll
        for (int j = 0; j < 4; j++)
            z[(size_t)(m0 + ty * 4 + i) * DIM + c0 + tx * 4 + j] = acc[i][j] + h_b[c0 + tx * 4 + j];
}

// ---------------- gather: out[i] = z[ix[i]] ----------------
__global__ void gather_kernel(const int* __restrict__ ix, const float4* __restrict__ z,
                              float4* __restrict__ out, int H) {
    int t = blockIdx.x * blockDim.x + threadIdx.x;
    int total = H * (DIM / 4);
    if (t < total) {
        int i = t / (DIM / 4);
        int q = t - i * (DIM / 4);
        out[(size_t)i * (DIM / 4) + q] = z[(size_t)ix[i] * (DIM / 4) + q];
    }
}

extern "C" void kernel_launch(void* const* d_in, const int* in_sizes, int n_in,
                              void* d_out, int out_size, void* d_ws, size_t ws_size,
                              hipStream_t stream) {
    const float* x   = (const float*)d_in[0];
    const int*   ix  = (const int*)d_in[1];
    const float* f_w = (const float*)d_in[2];
    const float* f_b = (const float*)d_in[3];
    const float* g_w = (const float*)d_in[4];
    const float* g_b = (const float*)d_in[5];
    const float* h_w = (const float*)d_in[6];
    const float* h_b = (const float*)d_in[7];
    float* out = (float*)d_out;
    const int H = in_sizes[0] / DIM;

    char* w = (char*)d_ws;
    int* hist      = (int*)w;            w += 4096;           // 1024 ints
    int* seg_start = (int*)w;            w += 8192;           // 1025 ints (padded)
    int* cursor    = (int*)w;            w += 4096;           // 1024 ints
    int* order     = (int*)w;            w += (size_t)H * 4;  // H ints
    float* num     = (float*)w;          w += (size_t)NSEG * DIM * 4;
    float* z       = (float*)w;          /* NSEG*DIM floats */

    hipMemsetAsync(hist, 0, NSEG * sizeof(int), stream);
    hist_kernel<<<(H + 255) / 256, 256, 0, stream>>>(ix, hist, H);
    scan_kernel<<<1, NSEG, 0, stream>>>(hist, seg_start, cursor);
    scatter_kernel<<<(H + 255) / 256, 256, 0, stream>>>(ix, cursor, order, H);
    seg_gemm_kernel<<<dim3(NSEG, 3), 256, 0, stream>>>(x, f_w, f_b, g_w, g_b,
                                                       order, seg_start, num);
    hgemm_kernel<<<dim3(NSEG / 64, DIM / 64), 256, 0, stream>>>(num, h_w, h_b, z);
    gather_kernel<<<(H * (DIM / 4) + 255) / 256, 256, 0, stream>>>(
        ix, (const float4*)z, (float4*)out, H);
}

// Round 2
// 502.718 us; speedup vs baseline: 1.9362x; 1.9362x over previous
//
#include <hip/hip_runtime.h>

#define DIM 384
#define NSEG 1024
#define LDA 392   // 384 + 8 bf16 pad: row stride 784B -> 2-way LDS conflict (free)

typedef __attribute__((ext_vector_type(8))) short bf16x8;
typedef __attribute__((ext_vector_type(4))) float f32x4;

static __device__ __forceinline__ short f2bf(float f) {
    union { float f; unsigned u; } v{f};
    unsigned r = (v.u + 0x7FFFu + ((v.u >> 16) & 1u)) >> 16;
    return (short)r;
}

// ---------------- counting sort ----------------

__global__ void hist_kernel(const int* __restrict__ ix, int* __restrict__ hist, int H) {
    int i = blockIdx.x * blockDim.x + threadIdx.x;
    if (i < H) atomicAdd(&hist[ix[i]], 1);
}

__global__ void scan_kernel(const int* __restrict__ hist, int* __restrict__ seg_start,
                            int* __restrict__ cursor) {
    __shared__ int tmp[NSEG];
    int t = threadIdx.x;
    int v = hist[t];
    tmp[t] = v;
    __syncthreads();
    for (int off = 1; off < NSEG; off <<= 1) {
        int add = (t >= off) ? tmp[t - off] : 0;
        __syncthreads();
        tmp[t] += add;
        __syncthreads();
    }
    int incl = tmp[t];
    seg_start[t] = incl - v;
    cursor[t]    = incl - v;
    if (t == NSEG - 1) seg_start[NSEG] = incl;
}

__global__ void scatter_kernel(const int* __restrict__ ix, int* __restrict__ cursor,
                               int* __restrict__ order, int H) {
    int i = blockIdx.x * blockDim.x + threadIdx.x;
    if (i < H) {
        int p = atomicAdd(&cursor[ix[i]], 1);
        order[p] = i;
    }
}

// ---------------- weight fp32 -> bf16 ----------------
__global__ void cvt_w_kernel(const float* __restrict__ fw, const float* __restrict__ gw,
                             short* __restrict__ fwb, short* __restrict__ gwb, int n) {
    int i = blockIdx.x * blockDim.x + threadIdx.x;
    if (i < n) { fwb[i] = f2bf(fw[i]); gwb[i] = f2bf(gw[i]); }
}

// ---------------- fused bf16-MFMA f/g GEMM + segment softmax reduce ----------------
// One block (512 thr = 8 waves) per segment. 32-row chunks staged bf16 into LDS.
// Wave w owns channels [w*48, w*48+48) for BOTH f and g (epilogue is wave-local).
// C/D layout (verified): col = lane&15, row = (lane>>4)*4 + reg.
__global__ __launch_bounds__(512) void seg_gemm_mfma(
    const float* __restrict__ x,
    const short* __restrict__ f_wb, const float* __restrict__ f_b,
    const short* __restrict__ g_wb, const float* __restrict__ g_b,
    const int* __restrict__ order, const int* __restrict__ seg_start,
    float* __restrict__ num) {
    const int seg  = blockIdx.x;
    const int tid  = threadIdx.x;
    const int lane = tid & 63;
    const int wave = tid >> 6;
    const int n    = lane & 15;   // MFMA col / B row index
    const int q    = lane >> 4;   // quad
    const int cb   = wave * 48;

    __shared__ short As[32 * LDA];

    const int p0  = seg_start[seg];
    const int p1  = seg_start[seg + 1];
    const int cnt = p1 - p0;

    if (cnt <= 0) {
        if (lane < 16) {
#pragma unroll
            for (int t = 0; t < 3; t++)
                num[(size_t)seg * DIM + cb + t * 16 + lane] = 0.f;
        }
        return;
    }

    // B fragment base pointers (weights are [out_ch][k], exactly B^T layout)
    const short* fp[3]; const short* gp[3];
    float fbv[3], gbv[3];
#pragma unroll
    for (int t = 0; t < 3; t++) {
        int ch = cb + t * 16 + n;
        fp[t] = f_wb + (size_t)ch * DIM + q * 8;
        gp[t] = g_wb + (size_t)ch * DIM + q * 8;
        fbv[t] = f_b[ch];
        gbv[t] = g_b[ch];
    }

    const int a_off0 = (0  + n) * LDA + q * 8;
    const int a_off1 = (16 + n) * LDA + q * 8;

    float rsw[3] = {0.f, 0.f, 0.f};
    float rsf[3] = {0.f, 0.f, 0.f};

    for (int chunk = 0; chunk < cnt; chunk += 32) {
        __syncthreads();
        // ---- stage 32 rows of x into LDS as bf16 ----
        {
            int r  = tid >> 4;    // 0..31
            int cq = tid & 15;
            int p  = p0 + chunk + r;
            if (p >= p1) p = p1 - 1;             // clamp; masked in epilogue
            int gr = order[p];
            const float4* xr = (const float4*)(x + (size_t)gr * DIM);
            short* dst = &As[r * LDA];
#pragma unroll
            for (int i = 0; i < 6; i++) {
                float4 v = xr[cq + 16 * i];
                short4 s = { f2bf(v.x), f2bf(v.y), f2bf(v.z), f2bf(v.w) };
                *(short4*)&dst[(cq + 16 * i) * 4] = s;
            }
        }
        __syncthreads();

        f32x4 accf[2][3], accg[2][3];
#pragma unroll
        for (int rt = 0; rt < 2; rt++)
#pragma unroll
            for (int t = 0; t < 3; t++) {
                accf[rt][t] = (f32x4){0.f, 0.f, 0.f, 0.f};
                accg[rt][t] = (f32x4){0.f, 0.f, 0.f, 0.f};
            }

#pragma unroll
        for (int ks = 0; ks < 12; ks++) {
            bf16x8 a0 = *(const bf16x8*)&As[a_off0 + ks * 32];
            bf16x8 a1 = *(const bf16x8*)&As[a_off1 + ks * 32];
#pragma unroll
            for (int t = 0; t < 3; t++) {
                bf16x8 bf = *(const bf16x8*)(fp[t] + ks * 32);
                bf16x8 bg = *(const bf16x8*)(gp[t] + ks * 32);
                accf[0][t] = __builtin_amdgcn_mfma_f32_16x16x32_bf16(a0, bf, accf[0][t], 0, 0, 0);
                accf[1][t] = __builtin_amdgcn_mfma_f32_16x16x32_bf16(a1, bf, accf[1][t], 0, 0, 0);
                accg[0][t] = __builtin_amdgcn_mfma_f32_16x16x32_bf16(a0, bg, accg[0][t], 0, 0, 0);
                accg[1][t] = __builtin_amdgcn_mfma_f32_16x16x32_bf16(a1, bg, accg[1][t], 0, 0, 0);
            }
        }

        // ---- epilogue: w = exp(clip(gx)), accumulate row sums (wave-local) ----
#pragma unroll
        for (int rt = 0; rt < 2; rt++) {
#pragma unroll
            for (int r = 0; r < 4; r++) {
                int m = rt * 16 + q * 4 + r;
                bool valid = (chunk + m) < cnt;
#pragma unroll
                for (int t = 0; t < 3; t++) {
                    if (valid) {
                        float gx = accg[rt][t][r] + gbv[t];
                        gx = fmaxf(-50.f, fminf(50.f, gx));
                        float w = __expf(gx);
                        rsw[t] += w;
                        rsf[t] += (accf[rt][t][r] + fbv[t]) * w;
                    }
                }
            }
        }
    }

    // ---- cross-quad reduce (rows live across quads), write num ----
#pragma unroll
    for (int t = 0; t < 3; t++) {
        float sw = rsw[t], sf = rsf[t];
        sw += __shfl_xor(sw, 16, 64); sw += __shfl_xor(sw, 32, 64);
        sf += __shfl_xor(sf, 16, 64); sf += __shfl_xor(sf, 32, 64);
        if (lane < 16) {
            float d = fmaxf(sw, 1e-9f);
            num[(size_t)seg * DIM + cb + t * 16 + lane] = sf / d;
        }
    }
}

// ---------------- small h GEMM: z = num @ h_w^T + h_b (fp32) ----------------
__global__ __launch_bounds__(256) void hgemm_kernel(
    const float* __restrict__ num, const float* __restrict__ h_w,
    const float* __restrict__ h_b, float* __restrict__ z) {
    const int m0 = blockIdx.x * 64;
    const int c0 = blockIdx.y * 64;
    const int tid = threadIdx.x;
    const int ty = tid >> 4, tx = tid & 15;
    __shared__ float As[16][64];
    __shared__ float Bs[16][64];
    float acc[4][4];
#pragma unroll
    for (int i = 0; i < 4; i++)
#pragma unroll
        for (int j = 0; j < 4; j++) acc[i][j] = 0.f;

    for (int k0 = 0; k0 < DIM; k0 += 16) {
        __syncthreads();
        {
            int m  = tid >> 2;
            int kq = (tid & 3) << 2;
            float4 v = *(const float4*)(num + (size_t)(m0 + m) * DIM + k0 + kq);
            As[kq + 0][m] = v.x; As[kq + 1][m] = v.y;
            As[kq + 2][m] = v.z; As[kq + 3][m] = v.w;
            float4 w = *(const float4*)(h_w + (size_t)(c0 + m) * DIM + k0 + kq);
            Bs[kq + 0][m] = w.x; Bs[kq + 1][m] = w.y;
            Bs[kq + 2][m] = w.z; Bs[kq + 3][m] = w.w;
        }
        __syncthreads();
#pragma unroll
        for (int kk = 0; kk < 16; kk++) {
            float a[4], b[4];
#pragma unroll
            for (int i = 0; i < 4; i++) a[i] = As[kk][ty * 4 + i];
#pragma unroll
            for (int j = 0; j < 4; j++) b[j] = Bs[kk][tx * 4 + j];
#pragma unroll
            for (int i = 0; i < 4; i++)
#pragma unroll
                for (int j = 0; j < 4; j++) acc[i][j] += a[i] * b[j];
        }
    }
#pragma unroll
    for (int i = 0; i < 4; i++)
#pragma unroll
        for (int j = 0; j < 4; j++)
            z[(size_t)(m0 + ty * 4 + i) * DIM + c0 + tx * 4 + j] = acc[i][j] + h_b[c0 + tx * 4 + j];
}

// ---------------- gather: out[i] = z[ix[i]] ----------------
__global__ void gather_kernel(const int* __restrict__ ix, const float4* __restrict__ z,
                              float4* __restrict__ out, int H) {
    int t = blockIdx.x * blockDim.x + threadIdx.x;
    int total = H * (DIM / 4);
    if (t < total) {
        int i = t / (DIM / 4);
        int qq = t - i * (DIM / 4);
        out[(size_t)i * (DIM / 4) + qq] = z[(size_t)ix[i] * (DIM / 4) + qq];
    }
}

extern "C" void kernel_launch(void* const* d_in, const int* in_sizes, int n_in,
                              void* d_out, int out_size, void* d_ws, size_t ws_size,
                              hipStream_t stream) {
    const float* x   = (const float*)d_in[0];
    const int*   ix  = (const int*)d_in[1];
    const float* f_w = (const float*)d_in[2];
    const float* f_b = (const float*)d_in[3];
    const float* g_w = (const float*)d_in[4];
    const float* g_b = (const float*)d_in[5];
    const float* h_w = (const float*)d_in[6];
    const float* h_b = (const float*)d_in[7];
    float* out = (float*)d_out;
    const int H = in_sizes[0] / DIM;

    char* w = (char*)d_ws;
    int* hist      = (int*)w;            w += 4096;                  // 1024 ints
    int* seg_start = (int*)w;            w += 8192;                  // 1025 ints (padded)
    int* cursor    = (int*)w;            w += 4096;                  // 1024 ints
    int* order     = (int*)w;            w += (size_t)H * 4;         // H ints
    float* num     = (float*)w;          w += (size_t)NSEG * DIM * 4;
    float* z       = (float*)w;          w += (size_t)NSEG * DIM * 4;
    short* f_wb    = (short*)w;          w += (size_t)DIM * DIM * 2;
    short* g_wb    = (short*)w;          /* DIM*DIM shorts */

    hipMemsetAsync(hist, 0, NSEG * sizeof(int), stream);
    hist_kernel<<<(H + 255) / 256, 256, 0, stream>>>(ix, hist, H);
    cvt_w_kernel<<<(DIM * DIM + 255) / 256, 256, 0, stream>>>(f_w, g_w, f_wb, g_wb, DIM * DIM);
    scan_kernel<<<1, NSEG, 0, stream>>>(hist, seg_start, cursor);
    scatter_kernel<<<(H + 255) / 256, 256, 0, stream>>>(ix, cursor, order, H);
    seg_gemm_mfma<<<NSEG, 512, 0, stream>>>(x, f_wb, f_b, g_wb, g_b,
                                            order, seg_start, num);
    hgemm_kernel<<<dim3(NSEG / 64, DIM / 64), 256, 0, stream>>>(num, h_w, h_b, z);
    gather_kernel<<<(H * (DIM / 4) + 255) / 256, 256, 0, stream>>>(
        ix, (const float4*)z, (float4*)out, H);
}

// Round 4
// 472.044 us; speedup vs baseline: 2.0620x; 1.0650x over previous
//
#include <hip/hip_runtime.h>

#define DIM 384
#define NSEG 1024
#define LDA 392   // 384 + 8 bf16 pad: row stride 784B -> 2-way LDS conflict (free)

typedef __attribute__((ext_vector_type(8))) short bf16x8;
typedef __attribute__((ext_vector_type(4))) float f32x4;

static __device__ __forceinline__ short f2bf(float f) {
    union { float f; unsigned u; } v{f};
    unsigned r = (v.u + 0x7FFFu + ((v.u >> 16) & 1u)) >> 16;
    return (short)r;
}

// ---------------- counting sort ----------------

__global__ void hist_kernel(const int* __restrict__ ix, int* __restrict__ hist, int H) {
    int i = blockIdx.x * blockDim.x + threadIdx.x;
    if (i < H) atomicAdd(&hist[ix[i]], 1);
}

__global__ void scan_kernel(const int* __restrict__ hist, int* __restrict__ seg_start,
                            int* __restrict__ cursor) {
    __shared__ int tmp[NSEG];
    int t = threadIdx.x;
    int v = hist[t];
    tmp[t] = v;
    __syncthreads();
    for (int off = 1; off < NSEG; off <<= 1) {
        int add = (t >= off) ? tmp[t - off] : 0;
        __syncthreads();
        tmp[t] += add;
        __syncthreads();
    }
    int incl = tmp[t];
    seg_start[t] = incl - v;
    cursor[t]    = incl - v;
    if (t == NSEG - 1) seg_start[NSEG] = incl;
}

__global__ void scatter_kernel(const int* __restrict__ ix, int* __restrict__ cursor,
                               int* __restrict__ order, int H) {
    int i = blockIdx.x * blockDim.x + threadIdx.x;
    if (i < H) {
        int p = atomicAdd(&cursor[ix[i]], 1);
        order[p] = i;
    }
}

// ---------------- weight fp32 -> bf16 ----------------
__global__ void cvt_w_kernel(const float* __restrict__ fw, const float* __restrict__ gw,
                             short* __restrict__ fwb, short* __restrict__ gwb, int n) {
    int i = blockIdx.x * blockDim.x + threadIdx.x;
    if (i < n) { fwb[i] = f2bf(fw[i]); gwb[i] = f2bf(gw[i]); }
}

// ---------------- fused bf16-MFMA f/g GEMM + segment softmax reduce ----------------
// One block (512 thr = 8 waves) per segment. 32-row chunks staged bf16 into LDS.
// x staging uses NONTEMPORAL loads so the 1.18 MB bf16 weight set stays
// L2-resident (R2 counters: 409 MB fetch = weights evicted by x stream).
// Wave w owns channels [w*48, w*48+48) for BOTH f and g (epilogue wave-local).
// C/D layout (verified): col = lane&15, row = (lane>>4)*4 + reg.
__global__ __launch_bounds__(512) void seg_gemm_mfma(
    const float* __restrict__ x,
    const short* __restrict__ f_wb, const float* __restrict__ f_b,
    const short* __restrict__ g_wb, const float* __restrict__ g_b,
    const int* __restrict__ order, const int* __restrict__ seg_start,
    float* __restrict__ num) {
    const int seg  = blockIdx.x;
    const int tid  = threadIdx.x;
    const int lane = tid & 63;
    const int wave = tid >> 6;
    const int n    = lane & 15;   // MFMA col / B row index
    const int q    = lane >> 4;   // quad
    const int cb   = wave * 48;

    __shared__ short As[32 * LDA];

    const int p0  = seg_start[seg];
    const int p1  = seg_start[seg + 1];
    const int cnt = p1 - p0;

    if (cnt <= 0) {
        if (lane < 16) {
#pragma unroll
            for (int t = 0; t < 3; t++)
                num[(size_t)seg * DIM + cb + t * 16 + lane] = 0.f;
        }
        return;
    }

    // B fragment base pointers (weights are [out_ch][k], exactly B^T layout)
    const short* fp[3]; const short* gp[3];
    float fbv[3], gbv[3];
#pragma unroll
    for (int t = 0; t < 3; t++) {
        int ch = cb + t * 16 + n;
        fp[t] = f_wb + (size_t)ch * DIM + q * 8;
        gp[t] = g_wb + (size_t)ch * DIM + q * 8;
        fbv[t] = f_b[ch];
        gbv[t] = g_b[ch];
    }

    const int a_off0 = (0  + n) * LDA + q * 8;
    const int a_off1 = (16 + n) * LDA + q * 8;

    float rsw[3] = {0.f, 0.f, 0.f};
    float rsf[3] = {0.f, 0.f, 0.f};

    for (int chunk = 0; chunk < cnt; chunk += 32) {
        __syncthreads();
        // ---- stage 32 rows of x into LDS as bf16 (nontemporal: use-once) ----
        {
            int r  = tid >> 4;    // 0..31
            int cq = tid & 15;
            int p  = p0 + chunk + r;
            if (p >= p1) p = p1 - 1;             // clamp; masked in epilogue
            int gr = order[p];
            const f32x4* xr = (const f32x4*)(x + (size_t)gr * DIM);
            short* dst = &As[r * LDA];
#pragma unroll
            for (int i = 0; i < 6; i++) {
                f32x4 v = __builtin_nontemporal_load(xr + cq + 16 * i);
                short4 s = { f2bf(v[0]), f2bf(v[1]), f2bf(v[2]), f2bf(v[3]) };
                *(short4*)&dst[(cq + 16 * i) * 4] = s;
            }
        }
        __syncthreads();

        f32x4 accf[2][3], accg[2][3];
#pragma unroll
        for (int rt = 0; rt < 2; rt++)
#pragma unroll
            for (int t = 0; t < 3; t++) {
                accf[rt][t] = (f32x4){0.f, 0.f, 0.f, 0.f};
                accg[rt][t] = (f32x4){0.f, 0.f, 0.f, 0.f};
            }

#pragma unroll
        for (int ks = 0; ks < 12; ks++) {
            bf16x8 a0 = *(const bf16x8*)&As[a_off0 + ks * 32];
            bf16x8 a1 = *(const bf16x8*)&As[a_off1 + ks * 32];
#pragma unroll
            for (int t = 0; t < 3; t++) {
                bf16x8 bf = *(const bf16x8*)(fp[t] + ks * 32);
                bf16x8 bg = *(const bf16x8*)(gp[t] + ks * 32);
                accf[0][t] = __builtin_amdgcn_mfma_f32_16x16x32_bf16(a0, bf, accf[0][t], 0, 0, 0);
                accf[1][t] = __builtin_amdgcn_mfma_f32_16x16x32_bf16(a1, bf, accf[1][t], 0, 0, 0);
                accg[0][t] = __builtin_amdgcn_mfma_f32_16x16x32_bf16(a0, bg, accg[0][t], 0, 0, 0);
                accg[1][t] = __builtin_amdgcn_mfma_f32_16x16x32_bf16(a1, bg, accg[1][t], 0, 0, 0);
            }
        }

        // ---- epilogue: w = exp(clip(gx)), accumulate row sums (wave-local) ----
#pragma unroll
        for (int rt = 0; rt < 2; rt++) {
#pragma unroll
            for (int r = 0; r < 4; r++) {
                int m = rt * 16 + q * 4 + r;
                bool valid = (chunk + m) < cnt;
#pragma unroll
                for (int t = 0; t < 3; t++) {
                    if (valid) {
                        float gx = accg[rt][t][r] + gbv[t];
                        gx = fmaxf(-50.f, fminf(50.f, gx));
                        float w = __expf(gx);
                        rsw[t] += w;
                        rsf[t] += (accf[rt][t][r] + fbv[t]) * w;
                    }
                }
            }
        }
    }

    // ---- cross-quad reduce (rows live across quads), write num ----
#pragma unroll
    for (int t = 0; t < 3; t++) {
        float sw = rsw[t], sf = rsf[t];
        sw += __shfl_xor(sw, 16, 64); sw += __shfl_xor(sw, 32, 64);
        sf += __shfl_xor(sf, 16, 64); sf += __shfl_xor(sf, 32, 64);
        if (lane < 16) {
            float d = fmaxf(sw, 1e-9f);
            num[(size_t)seg * DIM + cb + t * 16 + lane] = sf / d;
        }
    }
}

// ---------------- small h GEMM: z = num @ h_w^T + h_b (fp32) ----------------
__global__ __launch_bounds__(256) void hgemm_kernel(
    const float* __restrict__ num, const float* __restrict__ h_w,
    const float* __restrict__ h_b, float* __restrict__ z) {
    const int m0 = blockIdx.x * 64;
    const int c0 = blockIdx.y * 64;
    const int tid = threadIdx.x;
    const int ty = tid >> 4, tx = tid & 15;
    __shared__ float As[16][64];
    __shared__ float Bs[16][64];
    float acc[4][4];
#pragma unroll
    for (int i = 0; i < 4; i++)
#pragma unroll
        for (int j = 0; j < 4; j++) acc[i][j] = 0.f;

    for (int k0 = 0; k0 < DIM; k0 += 16) {
        __syncthreads();
        {
            int m  = tid >> 2;
            int kq = (tid & 3) << 2;
            float4 v = *(const float4*)(num + (size_t)(m0 + m) * DIM + k0 + kq);
            As[kq + 0][m] = v.x; As[kq + 1][m] = v.y;
            As[kq + 2][m] = v.z; As[kq + 3][m] = v.w;
            float4 w = *(const float4*)(h_w + (size_t)(c0 + m) * DIM + k0 + kq);
            Bs[kq + 0][m] = w.x; Bs[kq + 1][m] = w.y;
            Bs[kq + 2][m] = w.z; Bs[kq + 3][m] = w.w;
        }
        __syncthreads();
#pragma unroll
        for (int kk = 0; kk < 16; kk++) {
            float a[4], b[4];
#pragma unroll
            for (int i = 0; i < 4; i++) a[i] = As[kk][ty * 4 + i];
#pragma unroll
            for (int j = 0; j < 4; j++) b[j] = Bs[kk][tx * 4 + j];
#pragma unroll
            for (int i = 0; i < 4; i++)
#pragma unroll
                for (int j = 0; j < 4; j++) acc[i][j] += a[i] * b[j];
        }
    }
#pragma unroll
    for (int i = 0; i < 4; i++)
#pragma unroll
        for (int j = 0; j < 4; j++)
            z[(size_t)(m0 + ty * 4 + i) * DIM + c0 + tx * 4 + j] = acc[i][j] + h_b[c0 + tx * 4 + j];
}

// ---------------- gather: out[i] = z[ix[i]] (nt store: don't thrash L2) ----------------
__global__ void gather_kernel(const int* __restrict__ ix, const f32x4* __restrict__ z,
                              f32x4* __restrict__ out, int H) {
    int t = blockIdx.x * blockDim.x + threadIdx.x;
    int total = H * (DIM / 4);
    if (t < total) {
        int i = t / (DIM / 4);
        int qq = t - i * (DIM / 4);
        f32x4 v = z[(size_t)ix[i] * (DIM / 4) + qq];
        __builtin_nontemporal_store(v, out + (size_t)i * (DIM / 4) + qq);
    }
}

extern "C" void kernel_launch(void* const* d_in, const int* in_sizes, int n_in,
                              void* d_out, int out_size, void* d_ws, size_t ws_size,
                              hipStream_t stream) {
    const float* x   = (const float*)d_in[0];
    const int*   ix  = (const int*)d_in[1];
    const float* f_w = (const float*)d_in[2];
    const float* f_b = (const float*)d_in[3];
    const float* g_w = (const float*)d_in[4];
    const float* g_b = (const float*)d_in[5];
    const float* h_w = (const float*)d_in[6];
    const float* h_b = (const float*)d_in[7];
    float* out = (float*)d_out;
    const int H = in_sizes[0] / DIM;

    char* w = (char*)d_ws;
    int* hist      = (int*)w;            w += 4096;                  // 1024 ints
    int* seg_start = (int*)w;            w += 8192;                  // 1025 ints (padded)
    int* cursor    = (int*)w;            w += 4096;                  // 1024 ints
    int* order     = (int*)w;            w += (size_t)H * 4;         // H ints
    float* num     = (float*)w;          w += (size_t)NSEG * DIM * 4;
    float* z       = (float*)w;          w += (size_t)NSEG * DIM * 4;
    short* f_wb    = (short*)w;          w += (size_t)DIM * DIM * 2;
    short* g_wb    = (short*)w;          /* DIM*DIM shorts */

    (void)hipMemsetAsync(hist, 0, NSEG * sizeof(int), stream);
    hist_kernel<<<(H + 255) / 256, 256, 0, stream>>>(ix, hist, H);
    cvt_w_kernel<<<(DIM * DIM + 255) / 256, 256, 0, stream>>>(f_w, g_w, f_wb, g_wb, DIM * DIM);
    scan_kernel<<<1, NSEG, 0, stream>>>(hist, seg_start, cursor);
    scatter_kernel<<<(H + 255) / 256, 256, 0, stream>>>(ix, cursor, order, H);
    seg_gemm_mfma<<<NSEG, 512, 0, stream>>>(x, f_wb, f_b, g_wb, g_b,
                                            order, seg_start, num);
    hgemm_kernel<<<dim3(NSEG / 64, DIM / 64), 256, 0, stream>>>(num, h_w, h_b, z);
    gather_kernel<<<(H * (DIM / 4) + 255) / 256, 256, 0, stream>>>(
        ix, (const f32x4*)z, (f32x4*)out, H);
}

// Round 5
// 335.011 us; speedup vs baseline: 2.9055x; 1.4090x over previous
//
#include <hip/hip_runtime.h>

#define DIM 384
#define NSEG 1024
#define CHUNK 64        // rows per block
#define LDA 392         // shorts per LDS A row (384 + 8 pad)
#define MAXLS 16        // LDS segment slots per chunk (64-row sorted window spans ~2-3)

typedef __attribute__((ext_vector_type(8))) short bf16x8;
typedef __attribute__((ext_vector_type(4))) float f32x4;

static __device__ __forceinline__ short f2bf(float f) {
    union { float f; unsigned u; } v{f};
    unsigned r = (v.u + 0x7FFFu + ((v.u >> 16) & 1u)) >> 16;
    return (short)r;
}

// ---------------- counting sort ----------------

__global__ void hist_kernel(const int* __restrict__ ix, int* __restrict__ hist, int H) {
    int i = blockIdx.x * blockDim.x + threadIdx.x;
    if (i < H) atomicAdd(&hist[ix[i]], 1);
}

__global__ void scan_kernel(const int* __restrict__ hist, int* __restrict__ seg_start,
                            int* __restrict__ cursor) {
    __shared__ int tmp[NSEG];
    int t = threadIdx.x;
    int v = hist[t];
    tmp[t] = v;
    __syncthreads();
    for (int off = 1; off < NSEG; off <<= 1) {
        int add = (t >= off) ? tmp[t - off] : 0;
        __syncthreads();
        tmp[t] += add;
        __syncthreads();
    }
    int incl = tmp[t];
    seg_start[t] = incl - v;
    cursor[t]    = incl - v;
    if (t == NSEG - 1) seg_start[NSEG] = incl;
}

__global__ void scatter_kernel(const int* __restrict__ ix, int* __restrict__ cursor,
                               int* __restrict__ order, int H) {
    int i = blockIdx.x * blockDim.x + threadIdx.x;
    if (i < H) {
        int p = atomicAdd(&cursor[ix[i]], 1);
        order[p] = i;
    }
}

// ---------------- pack weights into MFMA B-fragment order ----------------
// pb[((mat*24 + T)*12 + ks)*512 + lane*8 + e] = W[T*16 + (lane&15)][ks*32 + (lane>>4)*8 + e]
// so a wave's B-load for (mat, tile T, ks) is one contiguous 1 KB region.
__global__ void pack_w_kernel(const float* __restrict__ fw, const float* __restrict__ gw,
                              short* __restrict__ pb) {
    int idx = blockIdx.x * 256 + threadIdx.x;
    if (idx >= 2 * 24 * 12 * 64) return;
    int lane = idx & 63;
    int ks   = (idx >> 6) % 12;
    int T    = ((idx >> 6) / 12) % 24;
    int mat  = idx / (64 * 12 * 24);
    const float* src = mat ? gw : fw;
    int ch = T * 16 + (lane & 15);
    int k0 = ks * 32 + (lane >> 4) * 8;
    short* dst = pb + (size_t)idx * 8;
#pragma unroll
    for (int e = 0; e < 8; e++) dst[e] = f2bf(src[(size_t)ch * DIM + k0 + e]);
}

// ---------------- fused chunk GEMM + segmented softmax reduce ----------------
// Grid = H/64 blocks; block b owns sorted positions [64b, 64b+64).
// 8 waves; wave w owns 48 channels (tiles 3w..3w+2) for BOTH f and g.
// Epilogue: run-compressed segmented reduction -> 16-slot LDS accumulator
// (reusing the A-tile LDS) -> global fp32 atomic partials den_acc/num_acc.
__global__ __launch_bounds__(512, 3) void seg_gemm_chunk(
    const float* __restrict__ x, const short* __restrict__ pb,
    const float* __restrict__ f_b, const float* __restrict__ g_b,
    const int* __restrict__ order, const int* __restrict__ ix,
    float* __restrict__ den_acc, float* __restrict__ num_acc) {
    const int chunk0 = blockIdx.x * CHUNK;
    const int tid  = threadIdx.x;
    const int lane = tid & 63;
    const int wave = tid >> 6;
    const int n    = lane & 15;
    const int q    = lane >> 4;
    const int cb   = wave * 48;

    __shared__ short As[CHUNK * LDA];     // 50176 B; aliased as float acc later
    __shared__ int   segrow[CHUNK];

    // ---- stage 64 rows of x (sorted order) as bf16; record segment ids ----
    {
        int r  = tid >> 3;   // 0..63
        int c8 = tid & 7;
        int gr = order[chunk0 + r];
        if (c8 == 0) segrow[r] = ix[gr];
        const f32x4* xr = (const f32x4*)(x + (size_t)gr * DIM);
        short* dst = &As[r * LDA];
#pragma unroll
        for (int i = 0; i < 12; i++) {
            f32x4 v = __builtin_nontemporal_load(xr + c8 + 8 * i);
            short4 s = { f2bf(v[0]), f2bf(v[1]), f2bf(v[2]), f2bf(v[3]) };
            *(short4*)&dst[(c8 + 8 * i) * 4] = s;
        }
    }
    __syncthreads();

    float fbv[3], gbv[3];
#pragma unroll
    for (int t = 0; t < 3; t++) {
        fbv[t] = f_b[cb + t * 16 + n];
        gbv[t] = g_b[cb + t * 16 + n];
    }

    f32x4 accf[4][3], accg[4][3];
#pragma unroll
    for (int rt = 0; rt < 4; rt++)
#pragma unroll
        for (int t = 0; t < 3; t++) {
            accf[rt][t] = (f32x4){0.f, 0.f, 0.f, 0.f};
            accg[rt][t] = (f32x4){0.f, 0.f, 0.f, 0.f};
        }

#pragma unroll
    for (int ks = 0; ks < 12; ks++) {
        bf16x8 a[4];
#pragma unroll
        for (int rt = 0; rt < 4; rt++)
            a[rt] = *(const bf16x8*)&As[(rt * 16 + n) * LDA + ks * 32 + q * 8];
#pragma unroll
        for (int t = 0; t < 3; t++) {
            int Tg = wave * 3 + t;
            bf16x8 bfr = *(const bf16x8*)(pb + ((size_t)((0 * 24 + Tg) * 12 + ks)) * 512 + lane * 8);
            bf16x8 bgr = *(const bf16x8*)(pb + ((size_t)((1 * 24 + Tg) * 12 + ks)) * 512 + lane * 8);
#pragma unroll
            for (int rt = 0; rt < 4; rt++) {
                accf[rt][t] = __builtin_amdgcn_mfma_f32_16x16x32_bf16(a[rt], bfr, accf[rt][t], 0, 0, 0);
                accg[rt][t] = __builtin_amdgcn_mfma_f32_16x16x32_bf16(a[rt], bgr, accg[rt][t], 0, 0, 0);
            }
        }
    }

    // ---- epilogue: segmented reduce via 16-slot LDS accumulator ----
    const int s0 = segrow[0];
    __syncthreads();                       // all A reads done; reuse LDS
    float* accs = (float*)As;              // [MAXLS][DIM][2]
    for (int i = tid; i < MAXLS * DIM * 2; i += 512) accs[i] = 0.f;
    __syncthreads();

#pragma unroll
    for (int t = 0; t < 3; t++) {
        int ch = cb + t * 16 + n;
        float rw = 0.f, rf = 0.f;
        int cur = -1;
#pragma unroll
        for (int rt = 0; rt < 4; rt++) {
#pragma unroll
            for (int r = 0; r < 4; r++) {
                int m  = rt * 16 + q * 4 + r;       // ascending in (rt, r)
                int ls = segrow[m] - s0;
                if (ls != cur) {
                    if (cur >= 0) {
                        if (cur < MAXLS) {
                            atomicAdd(&accs[(cur * DIM + ch) * 2 + 0], rw);
                            atomicAdd(&accs[(cur * DIM + ch) * 2 + 1], rf);
                        } else {
                            atomicAdd(&den_acc[(size_t)(s0 + cur) * DIM + ch], rw);
                            atomicAdd(&num_acc[(size_t)(s0 + cur) * DIM + ch], rf);
                        }
                    }
                    cur = ls; rw = 0.f; rf = 0.f;
                }
                float gx = accg[rt][t][r] + gbv[t];
                gx = fmaxf(-50.f, fminf(50.f, gx));
                float w = __expf(gx);
                rw += w;
                rf += (accf[rt][t][r] + fbv[t]) * w;
            }
        }
        if (cur < MAXLS) {
            atomicAdd(&accs[(cur * DIM + ch) * 2 + 0], rw);
            atomicAdd(&accs[(cur * DIM + ch) * 2 + 1], rf);
        } else {
            atomicAdd(&den_acc[(size_t)(s0 + cur) * DIM + ch], rw);
            atomicAdd(&num_acc[(size_t)(s0 + cur) * DIM + ch], rf);
        }
    }
    __syncthreads();

    // ---- flush used LDS slots to global partials ----
    int nls = segrow[CHUNK - 1] - s0 + 1;
    if (nls > MAXLS) nls = MAXLS;
    for (int i = tid; i < nls * DIM; i += 512) {
        int ls = i / DIM, ch = i - ls * DIM;
        float dw = accs[(ls * DIM + ch) * 2 + 0];
        float dn = accs[(ls * DIM + ch) * 2 + 1];
        if (dw != 0.f || dn != 0.f) {
            atomicAdd(&den_acc[(size_t)(s0 + ls) * DIM + ch], dw);
            atomicAdd(&num_acc[(size_t)(s0 + ls) * DIM + ch], dn);
        }
    }
}

// ---------------- small h GEMM: z = (num/den) @ h_w^T + h_b (fp32) ----------------
__global__ __launch_bounds__(256) void hgemm_kernel(
    const float* __restrict__ num, const float* __restrict__ den,
    const float* __restrict__ h_w, const float* __restrict__ h_b,
    float* __restrict__ z) {
    const int m0 = blockIdx.x * 64;
    const int c0 = blockIdx.y * 64;
    const int tid = threadIdx.x;
    const int ty = tid >> 4, tx = tid & 15;
    __shared__ float As[16][64];
    __shared__ float Bs[16][64];
    float acc[4][4];
#pragma unroll
    for (int i = 0; i < 4; i++)
#pragma unroll
        for (int j = 0; j < 4; j++) acc[i][j] = 0.f;

    for (int k0 = 0; k0 < DIM; k0 += 16) {
        __syncthreads();
        {
            int m  = tid >> 2;
            int kq = (tid & 3) << 2;
            size_t idx = (size_t)(m0 + m) * DIM + k0 + kq;
            float4 v = *(const float4*)(num + idx);
            float4 d = *(const float4*)(den + idx);
            v.x /= fmaxf(d.x, 1e-9f); v.y /= fmaxf(d.y, 1e-9f);
            v.z /= fmaxf(d.z, 1e-9f); v.w /= fmaxf(d.w, 1e-9f);
            As[kq + 0][m] = v.x; As[kq + 1][m] = v.y;
            As[kq + 2][m] = v.z; As[kq + 3][m] = v.w;
            float4 w = *(const float4*)(h_w + (size_t)(c0 + m) * DIM + k0 + kq);
            Bs[kq + 0][m] = w.x; Bs[kq + 1][m] = w.y;
            Bs[kq + 2][m] = w.z; Bs[kq + 3][m] = w.w;
        }
        __syncthreads();
#pragma unroll
        for (int kk = 0; kk < 16; kk++) {
            float a[4], b[4];
#pragma unroll
            for (int i = 0; i < 4; i++) a[i] = As[kk][ty * 4 + i];
#pragma unroll
            for (int j = 0; j < 4; j++) b[j] = Bs[kk][tx * 4 + j];
#pragma unroll
            for (int i = 0; i < 4; i++)
#pragma unroll
                for (int j = 0; j < 4; j++) acc[i][j] += a[i] * b[j];
        }
    }
#pragma unroll
    for (int i = 0; i < 4; i++)
#pragma unroll
        for (int j = 0; j < 4; j++)
            z[(size_t)(m0 + ty * 4 + i) * DIM + c0 + tx * 4 + j] = acc[i][j] + h_b[c0 + tx * 4 + j];
}

// ---------------- gather: out[i] = z[ix[i]] (nt store: don't thrash L2) ----------------
__global__ void gather_kernel(const int* __restrict__ ix, const f32x4* __restrict__ z,
                              f32x4* __restrict__ out, int H) {
    int t = blockIdx.x * blockDim.x + threadIdx.x;
    int total = H * (DIM / 4);
    if (t < total) {
        int i = t / (DIM / 4);
        int qq = t - i * (DIM / 4);
        f32x4 v = z[(size_t)ix[i] * (DIM / 4) + qq];
        __builtin_nontemporal_store(v, out + (size_t)i * (DIM / 4) + qq);
    }
}

extern "C" void kernel_launch(void* const* d_in, const int* in_sizes, int n_in,
                              void* d_out, int out_size, void* d_ws, size_t ws_size,
                              hipStream_t stream) {
    const float* x   = (const float*)d_in[0];
    const int*   ix  = (const int*)d_in[1];
    const float* f_w = (const float*)d_in[2];
    const float* f_b = (const float*)d_in[3];
    const float* g_w = (const float*)d_in[4];
    const float* g_b = (const float*)d_in[5];
    const float* h_w = (const float*)d_in[6];
    const float* h_b = (const float*)d_in[7];
    float* out = (float*)d_out;
    const int H = in_sizes[0] / DIM;

    char* w = (char*)d_ws;
    int* hist      = (int*)w;   w += 4096;                     // 1024 ints
    int* seg_start = (int*)w;   w += 8192;                     // 1025 ints (padded)
    int* cursor    = (int*)w;   w += 4096;                     // 1024 ints
    int* order     = (int*)w;   w += (size_t)H * 4;            // H ints
    float* den_acc = (float*)w; w += (size_t)NSEG * DIM * 4;   // zeroed below
    float* num_acc = (float*)w; w += (size_t)NSEG * DIM * 4;   // zeroed below (contiguous)
    float* z       = (float*)w; w += (size_t)NSEG * DIM * 4;
    short* pb      = (short*)w;                                // packed f+g weights, 1.18 MB

    (void)hipMemsetAsync(hist, 0, NSEG * sizeof(int), stream);
    (void)hipMemsetAsync(den_acc, 0, (size_t)2 * NSEG * DIM * 4, stream);
    hist_kernel<<<(H + 255) / 256, 256, 0, stream>>>(ix, hist, H);
    pack_w_kernel<<<(2 * 24 * 12 * 64 + 255) / 256, 256, 0, stream>>>(f_w, g_w, pb);
    scan_kernel<<<1, NSEG, 0, stream>>>(hist, seg_start, cursor);
    scatter_kernel<<<(H + 255) / 256, 256, 0, stream>>>(ix, cursor, order, H);
    seg_gemm_chunk<<<H / CHUNK, 512, 0, stream>>>(x, pb, f_b, g_b, order, ix,
                                                  den_acc, num_acc);
    hgemm_kernel<<<dim3(NSEG / 64, DIM / 64), 256, 0, stream>>>(num_acc, den_acc,
                                                                h_w, h_b, z);
    gather_kernel<<<(H * (DIM / 4) + 255) / 256, 256, 0, stream>>>(
        ix, (const f32x4*)z, (f32x4*)out, H);
}